// Round 7
// baseline (3005.024 us; speedup 1.0000x reference)
//
#include <hip/hip_runtime.h>
#include <math.h>

// Griffin-Lim inversion, fully-fused MFMA edition.
// One kernel per GL iteration: OA(FR) -> gemm1(STFT) -> phase-modify ->
// S in LDS (never global) -> gemm2(iSTFT) -> FR. 3-term bf16 splits
// (6 MFMAs, fp32-grade). FR double-buffered across dispatches (the OA
// halo reads neighbor rows other blocks rewrite -> ping-pong).

#define B_SZ 128
#define NFRM 256
#define BINS 128
#define NFFT 254
#define OUTL 16574
#define AUD  16384
#define GL_ITERS 50
#define MAXV 69.37411499023438f
#define PI2f 6.2831853071795864f

typedef __attribute__((ext_vector_type(8))) short short8;
typedef __attribute__((ext_vector_type(4))) float f32x4;

__device__ __forceinline__ unsigned short f2bf(float f) {     // RNE f32->bf16
  unsigned u = __float_as_uint(f);
  return (unsigned short)((u + 0x7FFFu + ((u >> 16) & 1u)) >> 16);
}
__device__ __forceinline__ float bf2f(unsigned short h) {
  return __uint_as_float(((unsigned)h) << 16);
}
__device__ __forceinline__ void split3(float v, short* h, short* m, short* l) {
  unsigned short hh = f2bf(v);
  float r1 = v - bf2f(hh);
  unsigned short mm = f2bf(r1);
  float r2 = r1 - bf2f(mm);
  *h = (short)hh; *m = (short)mm; *l = (short)f2bf(r2);
}

#define MFMA6(ACC, AH, AM, AL, BH, BM, BL)                                   \
  ACC = __builtin_amdgcn_mfma_f32_16x16x32_bf16(AH, BL, ACC, 0, 0, 0);       \
  ACC = __builtin_amdgcn_mfma_f32_16x16x32_bf16(AM, BM, ACC, 0, 0, 0);       \
  ACC = __builtin_amdgcn_mfma_f32_16x16x32_bf16(AL, BH, ACC, 0, 0, 0);       \
  ACC = __builtin_amdgcn_mfma_f32_16x16x32_bf16(AH, BM, ACC, 0, 0, 0);       \
  ACC = __builtin_amdgcn_mfma_f32_16x16x32_bf16(AM, BH, ACC, 0, 0, 0);       \
  ACC = __builtin_amdgcn_mfma_f32_16x16x32_bf16(AH, BH, ACC, 0, 0, 0);

// ---------------------------------------------------------------- tables ----
// Fragment order: tile (kc,nt): lane l elem j <- W[kc*32+(l>>4)*8+j][nt*16+(l&15)]
__global__ void tables_k(short* __restrict__ WfH, short* __restrict__ WfM,
                         short* __restrict__ WfL, short* __restrict__ WiH,
                         short* __restrict__ WiM, short* __restrict__ WiL,
                         unsigned* __restrict__ gmax) {
  int tid = blockIdx.x * blockDim.x + threadIdx.x;
  if (tid == 0) *gmax = 0u;
  if (tid >= 65536) return;
  int idx = tid;
  int j = idx & 7, l = (idx >> 3) & 63, nt = (idx >> 9) & 15, kc = idx >> 13;
  int krow = kc * 32 + ((l >> 4) << 3) + j;
  int ncol = (nt << 4) + (l & 15);
  float v1 = 0.f;
  if (krow < NFFT) {
    int kk = ncol >> 1;
    int m = (kk * krow) % NFFT;
    float ang = PI2f * (float)m / (float)NFFT;
    float wn = 0.5f - 0.5f * cosf(PI2f * (float)krow / (float)NFFT);
    v1 = wn * ((ncol & 1) ? -sinf(ang) : cosf(ang));
  }
  split3(v1, &WfH[idx], &WfM[idx], &WfL[idx]);
  float v2 = 0.f;
  if (ncol < NFFT) {
    int kk = krow >> 1;
    int m = (kk * ncol) % NFFT;
    float ang = PI2f * (float)m / (float)NFFT;
    float wn = 0.5f - 0.5f * cosf(PI2f * (float)ncol / (float)NFFT);
    float d = 0.f;
    int p = ncol & 63;
    for (int q = 0; q < 4; ++q) {
      int nn = p + 64 * q;
      if (nn < NFFT) { float w = 0.5f - 0.5f * cosf(PI2f * (float)nn / (float)NFFT); d += w * w; }
    }
    float sw = wn / d;
    float ak = (kk == 0 || kk == BINS - 1) ? 1.f : 2.f;
    v2 = sw * (ak / (float)NFFT) * ((krow & 1) ? -sinf(ang) : cosf(ang));
  }
  split3(v2, &WiH[idx], &WiM[idx], &WiL[idx]);
}

// ------------------------------------------------------------------- mag ----
__global__ void mag_k(const float* __restrict__ x, float* __restrict__ mag) {
  int i = blockIdx.x * 256 + threadIdx.x;          // 4194304 exact
  mag[i] = expf(5.f * (x[i] - 1.f)) * MAXV;
}

// ------------------------------------------------------ fused GL iteration --
// Block = (batch b, 64 frames from f0). 512 threads, 8 waves, 2 N-tiles/wave.
// S_lds swizzle: 8-short chunk c of row r stored at slot (c&~7)|((c^r)&7).
template <int FIRST>
__global__ __launch_bounds__(512) void iter_k(
    const float* __restrict__ FRsrc, float* __restrict__ FRdst,
    const float* __restrict__ mag,
    const short* __restrict__ WfH, const short* __restrict__ WfM,
    const short* __restrict__ WfL,
    const short* __restrict__ WiH, const short* __restrict__ WiM,
    const short* __restrict__ WiL) {
  __shared__ __align__(16) short wfsH[4288], wfsM[4288], wfsL[4288]; // 25.7 KB
  __shared__ __align__(16) short SH[16384], SM[16384], SL[16384];    // 96 KB

  int blk = blockIdx.x;
  int b = blk >> 2, f0 = (blk & 3) << 6;
  int tid = threadIdx.x, lane = tid & 63, wv = tid >> 6;
  int fgl = b * NFRM + f0;

  if (FIRST) {
    // S0 = (mag, 0), split3, swizzled into LDS
    int row = tid >> 3, xq = tid & 7;
    const float* mrow = mag + ((size_t)(fgl + row) << 7) + (xq << 4);
#pragma unroll
    for (int q = 0; q < 4; ++q) {
      float4 mg = *(const float4*)&mrow[q << 2];
      short h[8] __attribute__((aligned(16))), m[8] __attribute__((aligned(16))),
            l[8] __attribute__((aligned(16)));
#pragma unroll
      for (int u = 0; u < 4; ++u) {
        split3(((const float*)&mg)[u], &h[2 * u], &m[2 * u], &l[2 * u]);
        h[2 * u + 1] = 0; m[2 * u + 1] = 0; l[2 * u + 1] = 0;
      }
      int c = (xq << 2) + q;
      int slot = (c & ~7) | ((c ^ row) & 7);
      int p = (row << 8) + (slot << 3);
      *(short8*)&SH[p] = *(const short8*)h;
      *(short8*)&SM[p] = *(const short8*)m;
      *(short8*)&SL[p] = *(const short8*)l;
    }
  } else {
    const float* FRb = FRsrc + ((size_t)b << 16);
    // vectorized fused overlap-add -> split3 -> swizzled wfs
    for (int i4 = tid; i4 < 1072; i4 += 512) {
      int i = i4 << 2;
      int t = (f0 << 6) + i;
      int ft = t >> 6, cb = t & 63;
      float4 s = make_float4(0.f, 0.f, 0.f, 0.f);
#pragma unroll
      for (int d = 3; d >= 0; --d) {               // ascending f; extras exact 0
        int f = ft - d;
        if (f >= 0 && f <= 255) {
          float4 v = *(const float4*)&FRb[(f << 8) + cb + (d << 6)];
          s.x += v.x; s.y += v.y; s.z += v.z; s.w += v.w;
        }
      }
      if (i == 4284) { s.z = 0.f; s.w = 0.f; }     // pad samples 4286/4287
      short hh[4] __attribute__((aligned(8))), mm[4] __attribute__((aligned(8))),
            ll[4] __attribute__((aligned(8)));
      split3(s.x, &hh[0], &mm[0], &ll[0]);
      split3(s.y, &hh[1], &mm[1], &ll[1]);
      split3(s.z, &hh[2], &mm[2], &ll[2]);
      split3(s.w, &hh[3], &mm[3], &ll[3]);
      int q = i >> 3;
      int qs = (q & ~7) | ((q ^ (q >> 3)) & 7);
      int p = (qs << 3) | (i & 7);
      *(short4*)&wfsH[p] = *(const short4*)hh;
      *(short4*)&wfsM[p] = *(const short4*)mm;
      *(short4*)&wfsL[p] = *(const short4*)ll;
    }

    f32x4 acc1[4][2];
#pragma unroll
    for (int i = 0; i < 4; ++i) { acc1[i][0] = (f32x4){0,0,0,0}; acc1[i][1] = (f32x4){0,0,0,0}; }

    __syncthreads();                               // wfs ready

    // gemm1: X = A(wf) x Wf  (no barriers; B streamed from L2)
    for (int kc = 0; kc < 8; ++kc) {
      short8 Ah[4], Am[4], Al[4];
#pragma unroll
      for (int mt = 0; mt < 4; ++mt) {
        int frame = (mt << 4) + (lane & 15);
        int q = (frame << 3) + (kc << 2) + (lane >> 4);
        int qs = (q & ~7) | ((q ^ (q >> 3)) & 7);
        Ah[mt] = *(const short8*)&wfsH[qs << 3];
        Am[mt] = *(const short8*)&wfsM[qs << 3];
        Al[mt] = *(const short8*)&wfsL[qs << 3];
      }
#pragma unroll
      for (int nt = 0; nt < 2; ++nt) {
        int ntg = (wv << 1) + nt;
        size_t off = (((size_t)((kc << 4) + ntg) << 6) + lane) << 3;
        short8 bh = *(const short8*)(WfH + off);
        short8 bm = *(const short8*)(WfM + off);
        short8 bl = *(const short8*)(WfL + off);
#pragma unroll
        for (int mt = 0; mt < 4; ++mt) {
          MFMA6(acc1[mt][nt], Ah[mt], Am[mt], Al[mt], bh, bm, bl)
        }
      }
    }

    // phase-modify epilogue: spec = mag * X/|X|, split3 -> swizzled S_lds
#pragma unroll
    for (int mt = 0; mt < 4; ++mt)
#pragma unroll
      for (int nt = 0; nt < 2; ++nt) {
        int col = (((wv << 1) + nt) << 4) | (lane & 15);
        int bin = col >> 1;
#pragma unroll
        for (int r = 0; r < 4; ++r) {
          int row = (mt << 4) + ((lane >> 4) << 2) + r;
          float v = acc1[mt][nt][r];
          float sq = v * v;
          float s2 = sq + __shfl_xor(sq, 1, 64);   // re/im mate (IEEE add commutes)
          float mg = mag[((size_t)(fgl + row) << 7) + bin];
          float o;
          if (s2 == 0.f) o = (col & 1) ? 0.f : mg; // angle(0)=0
          else o = v * mg * rsqrtf(s2);
          short oh, om, ol;
          split3(o, &oh, &om, &ol);
          int c = col >> 3;
          int slot = (c & ~7) | ((c ^ row) & 7);
          int p = (row << 8) + (slot << 3) + (col & 7);
          SH[p] = oh; SM[p] = om; SL[p] = ol;
        }
      }
  }

  f32x4 acc2[4][2];
#pragma unroll
  for (int i = 0; i < 4; ++i) { acc2[i][0] = (f32x4){0,0,0,0}; acc2[i][1] = (f32x4){0,0,0,0}; }

  __syncthreads();                                 // S_lds ready

  // gemm2: FR = S x Wi  (A from swizzled LDS, B streamed from L2, no barriers)
  for (int kc = 0; kc < 8; ++kc) {
    short8 bh[2], bm[2], bl[2];
#pragma unroll
    for (int nt = 0; nt < 2; ++nt) {
      int ntg = (wv << 1) + nt;
      size_t off = (((size_t)((kc << 4) + ntg) << 6) + lane) << 3;
      bh[nt] = *(const short8*)(WiH + off);
      bm[nt] = *(const short8*)(WiM + off);
      bl[nt] = *(const short8*)(WiL + off);
    }
#pragma unroll
    for (int mt = 0; mt < 4; ++mt) {
      int rl = (mt << 4) + (lane & 15);
      int c = (kc << 2) + (lane >> 4);
      int slot = (c & ~7) | ((c ^ rl) & 7);
      int base = (rl << 8) + (slot << 3);
      short8 Ah = *(const short8*)&SH[base];
      short8 Am = *(const short8*)&SM[base];
      short8 Al = *(const short8*)&SL[base];
#pragma unroll
      for (int nt = 0; nt < 2; ++nt) {
        MFMA6(acc2[mt][nt], Ah, Am, Al, bh[nt], bm[nt], bl[nt])
      }
    }
  }

  float* FRo = FRdst + ((size_t)b << 16) + ((size_t)f0 << 8);
#pragma unroll
  for (int mt = 0; mt < 4; ++mt)
#pragma unroll
    for (int nt = 0; nt < 2; ++nt) {
      int col = (((wv << 1) + nt) << 4) | (lane & 15);
#pragma unroll
      for (int r = 0; r < 4; ++r) {
        int row = (mt << 4) + ((lane >> 4) << 2) + r;
        FRo[((size_t)row << 8) + col] = acc2[mt][nt][r];
      }
    }
}

// ------------------------------------------------- reductions (OA fused) ----
__global__ void redmax_k(const float* __restrict__ FR, unsigned* __restrict__ gmax) {
  __shared__ float red[16];
  int b = blockIdx.x;
  const float* FRb = FR + ((size_t)b << 16);
  float v = 0.f;
  for (int t = threadIdx.x; t < OUTL; t += 1024) {
    int f_hi = t >> 6; if (f_hi > NFRM - 1) f_hi = NFRM - 1;
    int f_lo = (t >= NFFT) ? (((t - NFFT) >> 6) + 1) : 0;
    float s = 0.f;
    for (int f = f_lo; f <= f_hi; ++f) s += FRb[(f << 8) + t - (f << 6)];
    v = fmaxf(v, fabsf(s));
  }
#pragma unroll
  for (int o = 32; o > 0; o >>= 1) v = fmaxf(v, __shfl_xor(v, o, 64));
  if ((threadIdx.x & 63) == 0) red[threadIdx.x >> 6] = v;
  __syncthreads();
  if (threadIdx.x < 16) {
    v = red[threadIdx.x];
#pragma unroll
    for (int o = 8; o > 0; o >>= 1) v = fmaxf(v, __shfl_xor(v, o, 16));
    if (threadIdx.x == 0) atomicMax(gmax, __float_as_uint(v));
  }
}

__global__ void out_k(const float* __restrict__ FR, const unsigned* __restrict__ gmax,
                      float* __restrict__ out) {
  int b = blockIdx.y, t = blockIdx.x * 256 + threadIdx.x;   // t < 16384
  const float* FRb = FR + ((size_t)b << 16);
  int f_hi = t >> 6; if (f_hi > NFRM - 1) f_hi = NFRM - 1;
  int f_lo = (t >= NFFT) ? (((t - NFFT) >> 6) + 1) : 0;
  float s = 0.f;
  for (int f = f_lo; f <= f_hi; ++f) s += FRb[(f << 8) + t - (f << 6)];
  float g = __uint_as_float(*gmax);
  out[(size_t)b * AUD + t] = s / g;
}

// ---------------------------------------------------------------- launch ----
extern "C" void kernel_launch(void* const* d_in, const int* in_sizes, int n_in,
                              void* d_out, int out_size, void* d_ws, size_t ws_size,
                              hipStream_t stream) {
  const float* x = (const float*)d_in[0];

  float* FR0 = (float*)d_ws;                       // 8,388,608 f
  float* FR1 = FR0 + 8388608;                      // 8,388,608 f
  float* mag = FR1 + 8388608;                      // 4,194,304 f
  short* WfH = (short*)(mag + 4194304);            // 65536 sh each
  short* WfM = WfH + 65536;
  short* WfL = WfM + 65536;
  short* WiH = WfL + 65536;
  short* WiM = WiH + 65536;
  short* WiL = WiM + 65536;
  unsigned* gmax = (unsigned*)(WiL + 65536);       // ~84.7 MB total

  mag_k<<<16384, 256, 0, stream>>>(x, mag);
  tables_k<<<256, 256, 0, stream>>>(WfH, WfM, WfL, WiH, WiM, WiL, gmax);

  // initial istft of (mag, 0) -> FR0
  iter_k<1><<<512, 512, 0, stream>>>(FR1, FR0, mag, WfH, WfM, WfL, WiH, WiM, WiL);

  float* bufs[2] = {FR0, FR1};
  for (int it = 0; it < GL_ITERS; ++it) {
    iter_k<0><<<512, 512, 0, stream>>>(bufs[it & 1], bufs[(it + 1) & 1], mag,
                                       WfH, WfM, WfL, WiH, WiM, WiL);
  }
  // 50 even -> final waveform frames in FR0

  redmax_k<<<B_SZ, 1024, 0, stream>>>(FR0, gmax);
  out_k<<<dim3(64, B_SZ), 256, 0, stream>>>(FR0, gmax, (float*)d_out);
}

// Round 10
// 2499.334 us; speedup vs baseline: 1.2023x; 1.2023x over previous
//
#include <hip/hip_runtime.h>
#include <math.h>

// Griffin-Lim inversion, fused bf16-3-term MFMA edition, M-tile=32.
// One kernel per GL iteration: OA(FR) -> gemm1(STFT) -> phase-modify ->
// S in LDS (48 KB) -> gemm2(iSTFT) -> FR.  v = h+m+l (bf16 x3, exact to
// 2^-26); 6 MFMAs per product.  Fusion is row-diagonal so M=32 blocks are
// independent; 64.6 KB LDS -> 2 blocks/CU.  Epilogue via fp32 tr-tile
// (aliased over dead wfs) -> vectorized 16B S writes (no bank-conflict
// scalar stores).  FR ping-pongs across dispatches.

#define B_SZ 128
#define NFRM 256
#define BINS 128
#define NFFT 254
#define OUTL 16574
#define AUD  16384
#define GL_ITERS 50
#define MAXV 69.37411499023438f
#define PI2f 6.2831853071795864f

typedef __attribute__((ext_vector_type(8))) short short8;
typedef __attribute__((ext_vector_type(4))) short short4v;
typedef __attribute__((ext_vector_type(4))) float f32x4;

__device__ __forceinline__ unsigned short f2bf(float f) {     // RNE f32->bf16
  unsigned u = __float_as_uint(f);
  return (unsigned short)((u + 0x7FFFu + ((u >> 16) & 1u)) >> 16);
}
__device__ __forceinline__ float bf2f(unsigned short h) {
  return __uint_as_float(((unsigned)h) << 16);
}
__device__ __forceinline__ void split3(float v, short* h, short* m, short* l) {
  unsigned short hh = f2bf(v);
  float r1 = v - bf2f(hh);
  unsigned short mm = f2bf(r1);
  float r2 = r1 - bf2f(mm);
  *h = (short)hh; *m = (short)mm; *l = (short)f2bf(r2);
}

// S-LDS swizzle: 16B chunk c of row r -> slot (c&~7)|((c^r^(r>>3))&7)
__device__ __forceinline__ int slotf(int c, int row) {
  return (c & ~7) | ((c ^ row ^ (row >> 3)) & 7);
}

#define MFMA6(ACC, AH, AM, AL, BH, BM, BL)                                   \
  ACC = __builtin_amdgcn_mfma_f32_16x16x32_bf16(AH, BL, ACC, 0, 0, 0);       \
  ACC = __builtin_amdgcn_mfma_f32_16x16x32_bf16(AM, BM, ACC, 0, 0, 0);       \
  ACC = __builtin_amdgcn_mfma_f32_16x16x32_bf16(AL, BH, ACC, 0, 0, 0);       \
  ACC = __builtin_amdgcn_mfma_f32_16x16x32_bf16(AH, BM, ACC, 0, 0, 0);       \
  ACC = __builtin_amdgcn_mfma_f32_16x16x32_bf16(AM, BH, ACC, 0, 0, 0);       \
  ACC = __builtin_amdgcn_mfma_f32_16x16x32_bf16(AH, BH, ACC, 0, 0, 0);

// ---------------------------------------------------------------- tables ----
// Fragment order: tile (kc,nt): lane l elem j <- W[kc*32+(l>>4)*8+j][nt*16+(l&15)]
__global__ void tables_k(short* __restrict__ WfH, short* __restrict__ WfM,
                         short* __restrict__ WfL, short* __restrict__ WiH,
                         short* __restrict__ WiM, short* __restrict__ WiL,
                         unsigned* __restrict__ gmax) {
  int tid = blockIdx.x * blockDim.x + threadIdx.x;
  if (tid == 0) *gmax = 0u;
  if (tid >= 65536) return;
  int idx = tid;
  int j = idx & 7, l = (idx >> 3) & 63, nt = (idx >> 9) & 15, kc = idx >> 13;
  int krow = kc * 32 + ((l >> 4) << 3) + j;
  int ncol = (nt << 4) + (l & 15);
  float v1 = 0.f;
  if (krow < NFFT) {
    int kk = ncol >> 1;
    int m = (kk * krow) % NFFT;
    float ang = PI2f * (float)m / (float)NFFT;
    float wn = 0.5f - 0.5f * cosf(PI2f * (float)krow / (float)NFFT);
    v1 = wn * ((ncol & 1) ? -sinf(ang) : cosf(ang));
  }
  split3(v1, &WfH[idx], &WfM[idx], &WfL[idx]);
  float v2 = 0.f;
  if (ncol < NFFT) {
    int kk = krow >> 1;
    int m = (kk * ncol) % NFFT;
    float ang = PI2f * (float)m / (float)NFFT;
    float wn = 0.5f - 0.5f * cosf(PI2f * (float)ncol / (float)NFFT);
    float d = 0.f;
    int p = ncol & 63;
    for (int q = 0; q < 4; ++q) {
      int nn = p + 64 * q;
      if (nn < NFFT) { float w = 0.5f - 0.5f * cosf(PI2f * (float)nn / (float)NFFT); d += w * w; }
    }
    float sw = wn / d;
    float ak = (kk == 0 || kk == BINS - 1) ? 1.f : 2.f;
    v2 = sw * (ak / (float)NFFT) * ((krow & 1) ? -sinf(ang) : cosf(ang));
  }
  split3(v2, &WiH[idx], &WiM[idx], &WiL[idx]);
}

// ------------------------------------------------------------------- mag ----
__global__ void mag_k(const float* __restrict__ x, float* __restrict__ mag) {
  int i = blockIdx.x * 256 + threadIdx.x;          // 4194304 exact
  mag[i] = expf(5.f * (x[i] - 1.f)) * MAXV;
}

// ------------------------------------------------------ fused GL iteration --
// Block = (batch b, 32 frames from f0 = (blk&7)*32). 512 threads, 8 waves.
// Wave: 2 M-tiles x 2 N-tiles (ntg = wv*2+nt covers all 256 cols).
template <int FIRST>
__global__ __launch_bounds__(512) void iter_k(
    const float* __restrict__ FRsrc, float* __restrict__ FRdst,
    const float* __restrict__ mag,
    const short* __restrict__ WfH, const short* __restrict__ WfM,
    const short* __restrict__ WfL,
    const short* __restrict__ WiH, const short* __restrict__ WiM,
    const short* __restrict__ WiL) {
  __shared__ __align__(16) short SH[8192], SM[8192], SL[8192];   // 48 KB
  __shared__ __align__(16) char scratch[16640];                  // wfs | tr
  short* wfsH = (short*)scratch;                   // 2240 each
  short* wfsM = wfsH + 2240;
  short* wfsL = wfsM + 2240;
  float* tr = (float*)scratch;                     // 16 x 260 f32

  int blk = blockIdx.x;
  int b = blk >> 3, f0 = (blk & 7) << 5;
  int tid = threadIdx.x, lane = tid & 63, wv = tid >> 6;
  int fgl = b * NFRM + f0;

  if (FIRST) {
    // S0 = (mag, 0), split3, swizzled into LDS
    int row = tid >> 4;                            // 0..31
#pragma unroll
    for (int q = 0; q < 2; ++q) {
      int c = ((tid & 15) << 1) + q;               // chunk 0..31
      float4 mg = *(const float4*)&mag[((size_t)(fgl + row) << 7) + (c << 2)];
      short h[8] __attribute__((aligned(16))), m[8] __attribute__((aligned(16))),
            l[8] __attribute__((aligned(16)));
#pragma unroll
      for (int u = 0; u < 4; ++u) {
        split3(((const float*)&mg)[u], &h[2 * u], &m[2 * u], &l[2 * u]);
        h[2 * u + 1] = 0; m[2 * u + 1] = 0; l[2 * u + 1] = 0;
      }
      int p = (row << 8) + (slotf(c, row) << 3);
      *(short8*)&SH[p] = *(const short8*)h;
      *(short8*)&SM[p] = *(const short8*)m;
      *(short8*)&SL[p] = *(const short8*)l;
    }
  } else {
    const float* FRb = FRsrc + ((size_t)b << 16);
    // vectorized fused overlap-add -> split3 -> swizzled wfs (2238 samples)
    for (int i4 = tid; i4 < 560; i4 += 512) {
      int i = i4 << 2;
      int t = (f0 << 6) + i;
      int ft = t >> 6, cb = t & 63;
      float4 s = make_float4(0.f, 0.f, 0.f, 0.f);
#pragma unroll
      for (int d = 3; d >= 0; --d) {               // ascending f; extras exact 0
        int f = ft - d;
        if (f >= 0 && f <= 255) {
          float4 v = *(const float4*)&FRb[(f << 8) + cb + (d << 6)];
          s.x += v.x; s.y += v.y; s.z += v.z; s.w += v.w;
        }
      }
      if (i == 2236) { s.z = 0.f; s.w = 0.f; }     // pad samples 2238/2239
      short hh[4] __attribute__((aligned(8))), mm[4] __attribute__((aligned(8))),
            ll[4] __attribute__((aligned(8)));
      split3(s.x, &hh[0], &mm[0], &ll[0]);
      split3(s.y, &hh[1], &mm[1], &ll[1]);
      split3(s.z, &hh[2], &mm[2], &ll[2]);
      split3(s.w, &hh[3], &mm[3], &ll[3]);
      int q = i >> 3;
      int qs = (q & ~7) | ((q ^ (q >> 3)) & 7);
      int p = (qs << 3) | (i & 7);
      *(short4v*)&wfsH[p] = *(const short4v*)hh;
      *(short4v*)&wfsM[p] = *(const short4v*)mm;
      *(short4v*)&wfsL[p] = *(const short4v*)ll;
    }

    f32x4 acc1[2][2];
#pragma unroll
    for (int i = 0; i < 2; ++i) { acc1[i][0] = (f32x4){0,0,0,0}; acc1[i][1] = (f32x4){0,0,0,0}; }

    __syncthreads();                               // wfs ready

    // gemm1: X = A(wf) x Wf  (no barriers; B streamed from L2)
    for (int kc = 0; kc < 8; ++kc) {
      short8 Ah[2], Am[2], Al[2];
#pragma unroll
      for (int mt = 0; mt < 2; ++mt) {
        int frame = (mt << 4) + (lane & 15);
        int q = (frame << 3) + (kc << 2) + (lane >> 4);
        int qs = (q & ~7) | ((q ^ (q >> 3)) & 7);
        Ah[mt] = *(const short8*)&wfsH[qs << 3];
        Am[mt] = *(const short8*)&wfsM[qs << 3];
        Al[mt] = *(const short8*)&wfsL[qs << 3];
      }
#pragma unroll
      for (int nt = 0; nt < 2; ++nt) {
        int ntg = (wv << 1) + nt;
        size_t off = (((size_t)((kc << 4) + ntg) << 6) + lane) << 3;
        short8 bh = *(const short8*)(WfH + off);
        short8 bm = *(const short8*)(WfM + off);
        short8 bl = *(const short8*)(WfL + off);
#pragma unroll
        for (int mt = 0; mt < 2; ++mt) {
          MFMA6(acc1[mt][nt], Ah[mt], Am[mt], Al[mt], bh, bm, bl)
        }
      }
    }

    // epilogue: 2 phases through fp32 tr tile (aliases dead wfs);
    // spec = mag*X/|X|; split3; vectorized 16B S writes.
    for (int mtg = 0; mtg < 2; ++mtg) {
      __syncthreads();                             // scratch free (wfs/tr reads done)
#pragma unroll
      for (int nt = 0; nt < 2; ++nt) {
        int col = (((wv << 1) + nt) << 4) | (lane & 15);
#pragma unroll
        for (int r = 0; r < 4; ++r) {
          int row16 = ((lane >> 4) << 2) + r;
          tr[row16 * 260 + col] = acc1[mtg][nt][r];
        }
      }
      __syncthreads();
      {
        int trow = tid >> 5;                       // 0..15
        int c = tid & 31;                          // chunk
        int c0 = c << 3;
        float4 va = *(const float4*)&tr[trow * 260 + c0];
        float4 vb = *(const float4*)&tr[trow * 260 + c0 + 4];
        int lrow = (mtg << 4) + trow;              // 0..31
        int srow = fgl + lrow;
        float4 xm = *(const float4*)&mag[((size_t)srow << 7) + (c << 2)];
        float vv[8] = {va.x, va.y, va.z, va.w, vb.x, vb.y, vb.z, vb.w};
        short hh[8] __attribute__((aligned(16))), mm[8] __attribute__((aligned(16))),
              ll[8] __attribute__((aligned(16)));
#pragma unroll
        for (int pq = 0; pq < 4; ++pq) {
          float mg = ((const float*)&xm)[pq];
          float re = vv[2 * pq], im = vv[2 * pq + 1];
          float s2 = re * re + im * im;
          float oe, oo;
          if (s2 == 0.f) { oe = mg; oo = 0.f; }    // angle(0)=0
          else { float rr = mg * rsqrtf(s2); oe = re * rr; oo = im * rr; }
          split3(oe, &hh[2 * pq], &mm[2 * pq], &ll[2 * pq]);
          split3(oo, &hh[2 * pq + 1], &mm[2 * pq + 1], &ll[2 * pq + 1]);
        }
        int p = (lrow << 8) + (slotf(c, lrow) << 3);
        *(short8*)&SH[p] = *(const short8*)hh;
        *(short8*)&SM[p] = *(const short8*)mm;
        *(short8*)&SL[p] = *(const short8*)ll;
      }
    }
  }

  f32x4 acc2[2][2];
#pragma unroll
  for (int i = 0; i < 2; ++i) { acc2[i][0] = (f32x4){0,0,0,0}; acc2[i][1] = (f32x4){0,0,0,0}; }

  __syncthreads();                                 // S_lds ready

  // gemm2: FR = S x Wi  (A from swizzled LDS, B streamed from L2, no barriers)
  for (int kc = 0; kc < 8; ++kc) {
    short8 bh[2], bm[2], bl[2];
#pragma unroll
    for (int nt = 0; nt < 2; ++nt) {
      int ntg = (wv << 1) + nt;
      size_t off = (((size_t)((kc << 4) + ntg) << 6) + lane) << 3;
      bh[nt] = *(const short8*)(WiH + off);
      bm[nt] = *(const short8*)(WiM + off);
      bl[nt] = *(const short8*)(WiL + off);
    }
#pragma unroll
    for (int mt = 0; mt < 2; ++mt) {
      int rl = (mt << 4) + (lane & 15);
      int c = (kc << 2) + (lane >> 4);
      int base = (rl << 8) + (slotf(c, rl) << 3);
      short8 Ah = *(const short8*)&SH[base];
      short8 Am = *(const short8*)&SM[base];
      short8 Al = *(const short8*)&SL[base];
#pragma unroll
      for (int nt = 0; nt < 2; ++nt) {
        MFMA6(acc2[mt][nt], Ah, Am, Al, bh[nt], bm[nt], bl[nt])
      }
    }
  }

  float* FRo = FRdst + ((size_t)b << 16) + ((size_t)f0 << 8);
#pragma unroll
  for (int mt = 0; mt < 2; ++mt)
#pragma unroll
    for (int nt = 0; nt < 2; ++nt) {
      int col = (((wv << 1) + nt) << 4) | (lane & 15);
#pragma unroll
      for (int r = 0; r < 4; ++r) {
        int row = (mt << 4) + ((lane >> 4) << 2) + r;
        FRo[((size_t)row << 8) + col] = acc2[mt][nt][r];
      }
    }
}

// ------------------------------------------------- reductions (OA fused) ----
__global__ void redmax_k(const float* __restrict__ FR, unsigned* __restrict__ gmax) {
  __shared__ float red[16];
  int b = blockIdx.x;
  const float* FRb = FR + ((size_t)b << 16);
  float v = 0.f;
  for (int t = threadIdx.x; t < OUTL; t += 1024) {
    int f_hi = t >> 6; if (f_hi > NFRM - 1) f_hi = NFRM - 1;
    int f_lo = (t >= NFFT) ? (((t - NFFT) >> 6) + 1) : 0;
    float s = 0.f;
    for (int f = f_lo; f <= f_hi; ++f) s += FRb[(f << 8) + t - (f << 6)];
    v = fmaxf(v, fabsf(s));
  }
#pragma unroll
  for (int o = 32; o > 0; o >>= 1) v = fmaxf(v, __shfl_xor(v, o, 64));
  if ((threadIdx.x & 63) == 0) red[threadIdx.x >> 6] = v;
  __syncthreads();
  if (threadIdx.x < 16) {
    v = red[threadIdx.x];
#pragma unroll
    for (int o = 8; o > 0; o >>= 1) v = fmaxf(v, __shfl_xor(v, o, 16));
    if (threadIdx.x == 0) atomicMax(gmax, __float_as_uint(v));
  }
}

__global__ void out_k(const float* __restrict__ FR, const unsigned* __restrict__ gmax,
                      float* __restrict__ out) {
  int b = blockIdx.y, t = blockIdx.x * 256 + threadIdx.x;   // t < 16384
  const float* FRb = FR + ((size_t)b << 16);
  int f_hi = t >> 6; if (f_hi > NFRM - 1) f_hi = NFRM - 1;
  int f_lo = (t >= NFFT) ? (((t - NFFT) >> 6) + 1) : 0;
  float s = 0.f;
  for (int f = f_lo; f <= f_hi; ++f) s += FRb[(f << 8) + t - (f << 6)];
  float g = __uint_as_float(*gmax);
  out[(size_t)b * AUD + t] = s / g;
}

// ---------------------------------------------------------------- launch ----
extern "C" void kernel_launch(void* const* d_in, const int* in_sizes, int n_in,
                              void* d_out, int out_size, void* d_ws, size_t ws_size,
                              hipStream_t stream) {
  const float* x = (const float*)d_in[0];

  float* FR0 = (float*)d_ws;                       // 8,388,608 f
  float* FR1 = FR0 + 8388608;                      // 8,388,608 f
  float* mag = FR1 + 8388608;                      // 4,194,304 f
  short* WfH = (short*)(mag + 4194304);            // 65536 sh each
  short* WfM = WfH + 65536;
  short* WfL = WfM + 65536;
  short* WiH = WfL + 65536;
  short* WiM = WiH + 65536;
  short* WiL = WiM + 65536;
  unsigned* gmax = (unsigned*)(WiL + 65536);       // ~85 MB total

  mag_k<<<16384, 256, 0, stream>>>(x, mag);
  tables_k<<<256, 256, 0, stream>>>(WfH, WfM, WfL, WiH, WiM, WiL, gmax);

  // initial istft of (mag, 0) -> FR0
  iter_k<1><<<1024, 512, 0, stream>>>(FR1, FR0, mag, WfH, WfM, WfL, WiH, WiM, WiL);

  float* bufs[2] = {FR0, FR1};
  for (int it = 0; it < GL_ITERS; ++it) {
    iter_k<0><<<1024, 512, 0, stream>>>(bufs[it & 1], bufs[(it + 1) & 1], mag,
                                        WfH, WfM, WfL, WiH, WiM, WiL);
  }
  // 50 even -> final waveform frames in FR0

  redmax_k<<<B_SZ, 1024, 0, stream>>>(FR0, gmax);
  out_k<<<dim3(64, B_SZ), 256, 0, stream>>>(FR0, gmax, (float*)d_out);
}